// Round 8
// baseline (229.573 us; speedup 1.0000x reference)
//
#include <hip/hip_runtime.h>

#define N_NODES 50000
#define N_EDGES 600000
#define D 128
#define K3 (3 * D)
#define NB_GEMM 782   // ceil(50000/64) row-tiles
#define NB_HIST 2344  // ceil(600000/256)

typedef __attribute__((ext_vector_type(8))) short short8;
typedef __attribute__((ext_vector_type(4))) float floatx4;
typedef __attribute__((ext_vector_type(8))) unsigned short ushort8;

static __device__ __forceinline__ unsigned short f2bf(float f) {
    unsigned u = __float_as_uint(f);
    u += 0x7fff + ((u >> 16) & 1);  // RNE
    return (unsigned short)(u >> 16);
}
static __device__ __forceinline__ float bf2f(unsigned short s) {
    return __uint_as_float(((unsigned)s) << 16);
}

// ---------------- W -> frag-ordered bf16 Wr ----------------
// chunk id = (T*4 + ks)*64 + lane, T in [0,24) colblocks over the 384-out space.
// chunk[j] = W[(T&7)*16 + c][(T>>3)*128 + ks*32 + q*8 + j]  (c=lane&15, q=lane>>4)
__global__ __launch_bounds__(256) void wconv_kernel(const float* __restrict__ W,
                                                    unsigned short* __restrict__ Wr) {
    unsigned id = blockIdx.x * 256 + threadIdx.x;
    if (id >= 24u * 4u * 64u) return;
    unsigned T = id >> 8;
    unsigned ks = (id >> 6) & 3u;
    unsigned lane = id & 63u;
    unsigned c = lane & 15u;
    unsigned q = lane >> 4;
    unsigned row = (T & 7u) * 16u + c;          // output index o
    unsigned k = (T >> 3) * 128u + ks * 32u + q * 8u;  // k within [0,384)
    const float4 v0 = *(const float4*)(W + (size_t)row * K3 + k);
    const float4 v1 = *(const float4*)(W + (size_t)row * K3 + k + 4);
    ushort8 o;
    o[0] = f2bf(v0.x); o[1] = f2bf(v0.y); o[2] = f2bf(v0.z); o[3] = f2bf(v0.w);
    o[4] = f2bf(v1.x); o[5] = f2bf(v1.y); o[6] = f2bf(v1.z); o[7] = f2bf(v1.w);
    *(ushort8*)(Wr + (size_t)id * 8) = o;
}

// ---------------- fused: [z1|z2|z3] = x @ W^T (+b into z1)  |  hist ----------------
// GEMM blocks: 64 rows/block, 4 waves; wave = 32 rows x 192 cols (12 colblocks).
// A from fp32 x (in-register RNE cvt), B from Wr (coalesced bf16, L2-hot).
__global__ __launch_bounds__(256) void setup_kernel(const float* __restrict__ x,
                                                    const unsigned short* __restrict__ Wr,
                                                    const float* __restrict__ bias,
                                                    const int* __restrict__ dst,
                                                    unsigned short* __restrict__ z1,
                                                    unsigned short* __restrict__ z2,
                                                    unsigned short* __restrict__ z3,
                                                    int* __restrict__ counts) {
    const int blk = blockIdx.x;
    if (blk >= NB_GEMM) {
        int e = (blk - NB_GEMM) * 256 + threadIdx.x;
        if (e < N_EDGES) atomicAdd(&counts[dst[e]], 1);
        return;
    }
    const int tid = threadIdx.x;
    const int wave = tid >> 6;
    const int lane = tid & 63;
    const int col = lane & 15;
    const int quad = lane >> 4;
    const int mbase = blk * 64 + (wave >> 1) * 32;
    const int tbase = (wave & 1) * 12;  // colblock range [tbase, tbase+12)

    int r0 = mbase + col;
    int r1 = mbase + 16 + col;
    if (r0 >= N_NODES) r0 = N_NODES - 1;  // clamp loads; stores guarded
    if (r1 >= N_NODES) r1 = N_NODES - 1;
    const float* ap0 = x + (size_t)r0 * D + quad * 8;
    const float* ap1 = x + (size_t)r1 * D + quad * 8;

    floatx4 acc0[12], acc1[12];
#pragma unroll
    for (int t = 0; t < 12; ++t) {
        acc0[t] = (floatx4){0.f, 0.f, 0.f, 0.f};
        acc1[t] = (floatx4){0.f, 0.f, 0.f, 0.f};
    }

#pragma unroll
    for (int ks = 0; ks < 4; ++ks) {
        float4 f00 = *(const float4*)(ap0 + ks * 32);
        float4 f01 = *(const float4*)(ap0 + ks * 32 + 4);
        float4 f10 = *(const float4*)(ap1 + ks * 32);
        float4 f11 = *(const float4*)(ap1 + ks * 32 + 4);
        short8 a0, a1;
        a0[0] = (short)f2bf(f00.x); a0[1] = (short)f2bf(f00.y);
        a0[2] = (short)f2bf(f00.z); a0[3] = (short)f2bf(f00.w);
        a0[4] = (short)f2bf(f01.x); a0[5] = (short)f2bf(f01.y);
        a0[6] = (short)f2bf(f01.z); a0[7] = (short)f2bf(f01.w);
        a1[0] = (short)f2bf(f10.x); a1[1] = (short)f2bf(f10.y);
        a1[2] = (short)f2bf(f10.z); a1[3] = (short)f2bf(f10.w);
        a1[4] = (short)f2bf(f11.x); a1[5] = (short)f2bf(f11.y);
        a1[6] = (short)f2bf(f11.z); a1[7] = (short)f2bf(f11.w);
#pragma unroll
        for (int t = 0; t < 12; ++t) {
            short8 bb = *(const short8*)(Wr + (size_t)(((tbase + t) * 4 + ks) * 64 + lane) * 8);
            acc0[t] = __builtin_amdgcn_mfma_f32_16x16x32_bf16(a0, bb, acc0[t], 0, 0, 0);
            acc1[t] = __builtin_amdgcn_mfma_f32_16x16x32_bf16(a1, bb, acc1[t], 0, 0, 0);
        }
    }

#pragma unroll
    for (int t = 0; t < 12; ++t) {
        int T = tbase + t;
        unsigned short* zb = (T < 8) ? z1 : ((T < 16) ? z2 : z3);
        int oc = (T & 7) * 16 + col;
        float bv = (T < 8) ? bias[oc] : 0.f;  // fold bias into z1
#pragma unroll
        for (int r = 0; r < 4; ++r) {
            int row0 = mbase + quad * 4 + r;
            int row1 = row0 + 16;
            if (row0 < N_NODES) zb[(size_t)row0 * D + oc] = f2bf(acc0[t][r] + bv);
            if (row1 < N_NODES) zb[(size_t)row1 * D + oc] = f2bf(acc1[t][r] + bv);
        }
    }
}

// ---------------- 3-phase scan (proven) ----------------
__global__ __launch_bounds__(256) void bsum_kernel(const int* __restrict__ counts,
                                                   int* __restrict__ bsum) {
    __shared__ int wsum[4];
    int tid = threadIdx.x;
    int i = blockIdx.x * 256 + tid;
    int v = (i < N_NODES) ? counts[i] : 0;
#pragma unroll
    for (int d = 32; d >= 1; d >>= 1) v += __shfl_xor(v, d);
    if ((tid & 63) == 0) wsum[tid >> 6] = v;
    __syncthreads();
    if (tid == 0) bsum[blockIdx.x] = wsum[0] + wsum[1] + wsum[2] + wsum[3];
}

__global__ __launch_bounds__(256) void scan_bsum_kernel(const int* __restrict__ bsum,
                                                        int* __restrict__ bexcl,
                                                        int* __restrict__ off, int nb) {
    __shared__ int wsum[4];
    int tid = threadIdx.x;
    int lane = tid & 63, wid = tid >> 6;
    int v = (tid < nb) ? bsum[tid] : 0;
    int x = v;
#pragma unroll
    for (int d = 1; d < 64; d <<= 1) {
        int u = __shfl_up(x, d);
        if (lane >= d) x += u;
    }
    if (lane == 63) wsum[wid] = x;
    __syncthreads();
    int prefix = 0;
    for (int w = 0; w < wid; ++w) prefix += wsum[w];
    if (tid < nb) bexcl[tid] = prefix + x - v;
    if (tid == 0) off[N_NODES] = N_EDGES;
}

__global__ __launch_bounds__(256) void scan_final_kernel(const int* __restrict__ counts,
                                                         const int* __restrict__ bexcl,
                                                         int* __restrict__ off,
                                                         int* __restrict__ cursor) {
    __shared__ int wsum[4];
    int tid = threadIdx.x;
    int lane = tid & 63, wid = tid >> 6;
    int i = blockIdx.x * 256 + tid;
    int v = (i < N_NODES) ? counts[i] : 0;
    int x = v;
#pragma unroll
    for (int d = 1; d < 64; d <<= 1) {
        int u = __shfl_up(x, d);
        if (lane >= d) x += u;
    }
    if (lane == 63) wsum[wid] = x;
    __syncthreads();
    int prefix = 0;
    for (int w = 0; w < wid; ++w) prefix += wsum[w];
    if (i < N_NODES) {
        int excl = bexcl[blockIdx.x] + prefix + x - v;
        off[i] = excl;
        cursor[i] = excl;
    }
}

// ---------------- CSR fill ----------------
__global__ __launch_bounds__(256) void fill_kernel(const int* __restrict__ src,
                                                   const int* __restrict__ dst,
                                                   int* __restrict__ cursor,
                                                   int* __restrict__ csr_src) {
    int e = blockIdx.x * blockDim.x + threadIdx.x;
    if (e < N_EDGES) {
        int pos = atomicAdd(&cursor[dst[e]], 1);
        csr_src[pos] = src[e];
    }
}

// ---------------- gather1: t = z2 + P z3  (bf16 out) ----------------
// one wave/node; lane = slot*16 + colchunk; int4-aligned index group loads.
__global__ __launch_bounds__(256) void gather1_kernel(const unsigned short* __restrict__ z3,
                                                      const unsigned short* __restrict__ z2,
                                                      const int* __restrict__ off,
                                                      const int* __restrict__ csr_src,
                                                      unsigned short* __restrict__ tb) {
    unsigned n = (blockIdx.x * 256 + threadIdx.x) >> 6;
    if (n >= N_NODES) return;
    const int lane = threadIdx.x & 63;
    const int s = lane >> 4;
    const unsigned c = (lane & 15u) << 3;
    const unsigned short* fin = z3 + c;
    const int2 ee = *(const int2*)(off + n);
    const int e0 = ee.x, e1 = ee.y;
    float acc[8] = {0.f, 0.f, 0.f, 0.f, 0.f, 0.f, 0.f, 0.f};
    for (int base = (e0 & ~3) + s * 4; base < e1; base += 16) {
        int4 idx = *(const int4*)(csr_src + base);
        float m0 = (base >= e0 && base < e1) ? 1.f : 0.f;
        float m1 = (base + 1 >= e0 && base + 1 < e1) ? 1.f : 0.f;
        float m2 = (base + 2 >= e0 && base + 2 < e1) ? 1.f : 0.f;
        float m3 = (base + 3 >= e0 && base + 3 < e1) ? 1.f : 0.f;
        int s0 = min(max(idx.x, 0), N_NODES - 1);
        int s1 = min(max(idx.y, 0), N_NODES - 1);
        int s2 = min(max(idx.z, 0), N_NODES - 1);
        int s3 = min(max(idx.w, 0), N_NODES - 1);
        ushort8 v0 = *(const ushort8*)(fin + (size_t)s0 * D);
        ushort8 v1 = *(const ushort8*)(fin + (size_t)s1 * D);
        ushort8 v2 = *(const ushort8*)(fin + (size_t)s2 * D);
        ushort8 v3 = *(const ushort8*)(fin + (size_t)s3 * D);
#pragma unroll
        for (int j = 0; j < 8; ++j)
            acc[j] += (m0 * bf2f(v0[j]) + m1 * bf2f(v1[j])) +
                      (m2 * bf2f(v2[j]) + m3 * bf2f(v3[j]));
    }
#pragma unroll
    for (int j = 0; j < 8; ++j) {
        acc[j] += __shfl_xor(acc[j], 16);
        acc[j] += __shfl_xor(acc[j], 32);
    }
    if (s == 0) {
        float inv = 1.0f / fmaxf((float)(e1 - e0), 1.0f);
        ushort8 za = *(const ushort8*)(z2 + (size_t)n * D + c);
        ushort8 o;
#pragma unroll
        for (int j = 0; j < 8; ++j) o[j] = f2bf(bf2f(za[j]) + acc[j] * inv);
        *(ushort8*)(tb + (size_t)n * D + c) = o;
    }
}

// ---------------- gather2: out = z1 + P t  (fp32 out, final) ----------------
__global__ __launch_bounds__(256) void gather2_kernel(const unsigned short* __restrict__ tb,
                                                      const unsigned short* __restrict__ z1,
                                                      const int* __restrict__ off,
                                                      const int* __restrict__ csr_src,
                                                      float* __restrict__ out) {
    unsigned n = (blockIdx.x * 256 + threadIdx.x) >> 6;
    if (n >= N_NODES) return;
    const int lane = threadIdx.x & 63;
    const int s = lane >> 4;
    const unsigned c = (lane & 15u) << 3;
    const unsigned short* fin = tb + c;
    const int2 ee = *(const int2*)(off + n);
    const int e0 = ee.x, e1 = ee.y;
    float acc[8] = {0.f, 0.f, 0.f, 0.f, 0.f, 0.f, 0.f, 0.f};
    for (int base = (e0 & ~3) + s * 4; base < e1; base += 16) {
        int4 idx = *(const int4*)(csr_src + base);
        float m0 = (base >= e0 && base < e1) ? 1.f : 0.f;
        float m1 = (base + 1 >= e0 && base + 1 < e1) ? 1.f : 0.f;
        float m2 = (base + 2 >= e0 && base + 2 < e1) ? 1.f : 0.f;
        float m3 = (base + 3 >= e0 && base + 3 < e1) ? 1.f : 0.f;
        int s0 = min(max(idx.x, 0), N_NODES - 1);
        int s1 = min(max(idx.y, 0), N_NODES - 1);
        int s2 = min(max(idx.z, 0), N_NODES - 1);
        int s3 = min(max(idx.w, 0), N_NODES - 1);
        ushort8 v0 = *(const ushort8*)(fin + (size_t)s0 * D);
        ushort8 v1 = *(const ushort8*)(fin + (size_t)s1 * D);
        ushort8 v2 = *(const ushort8*)(fin + (size_t)s2 * D);
        ushort8 v3 = *(const ushort8*)(fin + (size_t)s3 * D);
#pragma unroll
        for (int j = 0; j < 8; ++j)
            acc[j] += (m0 * bf2f(v0[j]) + m1 * bf2f(v1[j])) +
                      (m2 * bf2f(v2[j]) + m3 * bf2f(v3[j]));
    }
#pragma unroll
    for (int j = 0; j < 8; ++j) {
        acc[j] += __shfl_xor(acc[j], 16);
        acc[j] += __shfl_xor(acc[j], 32);
    }
    if (s == 0) {
        float inv = 1.0f / fmaxf((float)(e1 - e0), 1.0f);
        ushort8 za = *(const ushort8*)(z1 + (size_t)n * D + c);
        float4 q0, q1;
        q0.x = bf2f(za[0]) + acc[0] * inv;
        q0.y = bf2f(za[1]) + acc[1] * inv;
        q0.z = bf2f(za[2]) + acc[2] * inv;
        q0.w = bf2f(za[3]) + acc[3] * inv;
        q1.x = bf2f(za[4]) + acc[4] * inv;
        q1.y = bf2f(za[5]) + acc[5] * inv;
        q1.z = bf2f(za[6]) + acc[6] * inv;
        q1.w = bf2f(za[7]) + acc[7] * inv;
        *(float4*)(out + (size_t)n * D + c) = q0;
        *(float4*)(out + (size_t)n * D + c + 4) = q1;
    }
}

extern "C" void kernel_launch(void* const* d_in, const int* in_sizes, int n_in,
                              void* d_out, int out_size, void* d_ws, size_t ws_size,
                              hipStream_t stream) {
    const float* x = (const float*)d_in[0];
    const int* ei = (const int*)d_in[1];
    const float* W = (const float*)d_in[2];
    const float* b = (const float*)d_in[3];
    float* out = (float*)d_out;
    const int* src = ei;            // edge_index[0,:]
    const int* dst = ei + N_EDGES;  // edge_index[1,:]

    // workspace layout (bf16 [N,128] each = 12.8 MB):
    //   z1 (x W1^T + b) | z2 | z3 | tb (z2 + P z3)
    //   Wr 6144x16B | off [N+1] | cursor [N] | bsum/bexcl | csr_src [E+16]
    unsigned short* z1 = (unsigned short*)d_ws;
    unsigned short* z2 = z1 + (size_t)N_NODES * D;
    unsigned short* z3 = z2 + (size_t)N_NODES * D;
    unsigned short* tb = z3 + (size_t)N_NODES * D;
    unsigned short* Wr = tb + (size_t)N_NODES * D;
    int* off = (int*)(Wr + 6144 * 8);
    int* cursor = off + (N_NODES + 1);
    int* bsum = cursor + N_NODES;
    int* bexcl = bsum + 256;
    int* csr_src = bexcl + 256;

    const int NB = (N_NODES + 255) / 256;  // 196

    hipMemsetAsync(cursor, 0, (size_t)N_NODES * sizeof(int), stream);

    wconv_kernel<<<24, 256, 0, stream>>>(W, Wr);
    setup_kernel<<<NB_GEMM + NB_HIST, 256, 0, stream>>>(x, Wr, b, dst, z1, z2, z3, cursor);
    bsum_kernel<<<NB, 256, 0, stream>>>(cursor, bsum);
    scan_bsum_kernel<<<1, 256, 0, stream>>>(bsum, bexcl, off, NB);
    scan_final_kernel<<<NB, 256, 0, stream>>>(cursor, bexcl, off, cursor);
    fill_kernel<<<(N_EDGES + 255) / 256, 256, 0, stream>>>(src, dst, cursor, csr_src);

    const int ggrid = (N_NODES * 64 + 255) / 256;  // one wave per node
    gather1_kernel<<<ggrid, 256, 0, stream>>>(z3, z2, off, csr_src, tb);
    gather2_kernel<<<ggrid, 256, 0, stream>>>(tb, z1, off, csr_src, out);
}

// Round 10
// 213.968 us; speedup vs baseline: 1.0729x; 1.0729x over previous
//
#include <hip/hip_runtime.h>

#define N_NODES 50000
#define N_EDGES 600000
#define D 128
#define K3 (3 * D)
#define NB_G 1563   // ceil(50000/32) gemm row-tiles
#define NB_H 2344   // ceil(600000/256) hist blocks

typedef __attribute__((ext_vector_type(8))) short short8;
typedef __attribute__((ext_vector_type(4))) float floatx4;
typedef __attribute__((ext_vector_type(8))) unsigned short ushort8;

static __device__ __forceinline__ unsigned short f2bf(float f) {
    unsigned u = __float_as_uint(f);
    u += 0x7fff + ((u >> 16) & 1);  // RNE
    return (unsigned short)(u >> 16);
}
static __device__ __forceinline__ float bf2f(unsigned short s) {
    return __uint_as_float(((unsigned)s) << 16);
}

// ---------------- prep: zero counts | x->bf16 xb | W->frag-ordered Wr ------------
__global__ __launch_bounds__(256) void prep_kernel(const float* __restrict__ x,
                                                   const float* __restrict__ W,
                                                   unsigned short* __restrict__ xb,
                                                   unsigned short* __restrict__ Wr,
                                                   int* __restrict__ counts) {
    const int stride = gridDim.x * 256;
    const int t0 = blockIdx.x * 256 + threadIdx.x;
    for (int i = t0; i < N_NODES; i += stride) counts[i] = 0;
    for (unsigned t = t0; t < (unsigned)N_NODES * 16; t += stride) {
        unsigned n = t >> 4;
        unsigned c = (t & 15u) << 3;
        const float4 v0 = *(const float4*)(x + (size_t)n * D + c);
        const float4 v1 = *(const float4*)(x + (size_t)n * D + c + 4);
        ushort8 o;
        o[0] = f2bf(v0.x); o[1] = f2bf(v0.y); o[2] = f2bf(v0.z); o[3] = f2bf(v0.w);
        o[4] = f2bf(v1.x); o[5] = f2bf(v1.y); o[6] = f2bf(v1.z); o[7] = f2bf(v1.w);
        *(ushort8*)(xb + (size_t)n * D + c) = o;
    }
    // Wr chunk id = (T*4+ks)*64+lane; value[j] = W[(T&7)*16+c][(T>>3)*128+ks*32+q*8+j]
    for (unsigned id = t0; id < 24u * 4u * 64u; id += stride) {
        unsigned T = id >> 8;
        unsigned ks = (id >> 6) & 3u;
        unsigned lane = id & 63u;
        unsigned c = lane & 15u;
        unsigned q = lane >> 4;
        unsigned row = (T & 7u) * 16u + c;
        unsigned k = (T >> 3) * 128u + ks * 32u + q * 8u;
        const float4 v0 = *(const float4*)(W + (size_t)row * K3 + k);
        const float4 v1 = *(const float4*)(W + (size_t)row * K3 + k + 4);
        ushort8 o;
        o[0] = f2bf(v0.x); o[1] = f2bf(v0.y); o[2] = f2bf(v0.z); o[3] = f2bf(v0.w);
        o[4] = f2bf(v1.x); o[5] = f2bf(v1.y); o[6] = f2bf(v1.z); o[7] = f2bf(v1.w);
        *(ushort8*)(Wr + (size_t)id * 8) = o;
    }
}

// ---------------- fused: z[N,384] = xb @ Wcat^T (+bias on cols<128) | hist -------
// GEMM blocks: 32 rows/block, 4 waves; wave = 32 rows x 96 cols (6 colblocks).
// z cols [0,128)=z1(+bias), [128,256)=z2, [256,384)=z3.
__global__ __launch_bounds__(256) void gemmhist_kernel(const unsigned short* __restrict__ xb,
                                                       const unsigned short* __restrict__ Wr,
                                                       const float* __restrict__ bias,
                                                       const int* __restrict__ dst,
                                                       unsigned short* __restrict__ z,
                                                       int* __restrict__ counts) {
    const int blk = blockIdx.x;
    if (blk >= NB_G) {
        int e = (blk - NB_G) * 256 + threadIdx.x;
        if (e < N_EDGES) atomicAdd(&counts[dst[e]], 1);
        return;
    }
    const int tid = threadIdx.x;
    const int wave = tid >> 6;
    const int lane = tid & 63;
    const int col = lane & 15;
    const int quad = lane >> 4;
    const int mbase = blk * 32;
    const int T0 = wave * 6;  // colblocks [T0, T0+6)

    int r0 = mbase + col;
    int r1 = mbase + 16 + col;
    if (r0 >= N_NODES) r0 = N_NODES - 1;  // clamp loads; stores guarded
    if (r1 >= N_NODES) r1 = N_NODES - 1;
    const unsigned short* ap0 = xb + (size_t)r0 * D + quad * 8;
    const unsigned short* ap1 = xb + (size_t)r1 * D + quad * 8;

    floatx4 acc0[6], acc1[6];
#pragma unroll
    for (int t = 0; t < 6; ++t) {
        acc0[t] = (floatx4){0.f, 0.f, 0.f, 0.f};
        acc1[t] = (floatx4){0.f, 0.f, 0.f, 0.f};
    }

#pragma unroll
    for (int ks = 0; ks < 4; ++ks) {
        short8 a0 = *(const short8*)(ap0 + ks * 32);
        short8 a1 = *(const short8*)(ap1 + ks * 32);
#pragma unroll
        for (int t = 0; t < 6; ++t) {
            short8 bb = *(const short8*)(Wr + (size_t)(((T0 + t) * 4 + ks) * 64 + lane) * 8);
            acc0[t] = __builtin_amdgcn_mfma_f32_16x16x32_bf16(a0, bb, acc0[t], 0, 0, 0);
            acc1[t] = __builtin_amdgcn_mfma_f32_16x16x32_bf16(a1, bb, acc1[t], 0, 0, 0);
        }
    }

#pragma unroll
    for (int t = 0; t < 6; ++t) {
        int T = T0 + t;
        int j = T * 16 + col;                // z column in [0,384)
        float bv = (T < 8) ? bias[j] : 0.f;  // bias folds into z1 cols [0,128)
#pragma unroll
        for (int r = 0; r < 4; ++r) {
            int row0 = mbase + quad * 4 + r;
            int row1 = row0 + 16;
            if (row0 < N_NODES) z[(size_t)row0 * K3 + j] = f2bf(acc0[t][r] + bv);
            if (row1 < N_NODES) z[(size_t)row1 * K3 + j] = f2bf(acc1[t][r] + bv);
        }
    }
}

// ---------------- 3-phase scan (proven) ----------------
__global__ __launch_bounds__(256) void bsum_kernel(const int* __restrict__ counts,
                                                   int* __restrict__ bsum) {
    __shared__ int wsum[4];
    int tid = threadIdx.x;
    int i = blockIdx.x * 256 + tid;
    int v = (i < N_NODES) ? counts[i] : 0;
#pragma unroll
    for (int d = 32; d >= 1; d >>= 1) v += __shfl_xor(v, d);
    if ((tid & 63) == 0) wsum[tid >> 6] = v;
    __syncthreads();
    if (tid == 0) bsum[blockIdx.x] = wsum[0] + wsum[1] + wsum[2] + wsum[3];
}

__global__ __launch_bounds__(256) void scan_bsum_kernel(const int* __restrict__ bsum,
                                                        int* __restrict__ bexcl,
                                                        int* __restrict__ off, int nb) {
    __shared__ int wsum[4];
    int tid = threadIdx.x;
    int lane = tid & 63, wid = tid >> 6;
    int v = (tid < nb) ? bsum[tid] : 0;
    int x = v;
#pragma unroll
    for (int d = 1; d < 64; d <<= 1) {
        int u = __shfl_up(x, d);
        if (lane >= d) x += u;
    }
    if (lane == 63) wsum[wid] = x;
    __syncthreads();
    int prefix = 0;
    for (int w = 0; w < wid; ++w) prefix += wsum[w];
    if (tid < nb) bexcl[tid] = prefix + x - v;
    if (tid == 0) off[N_NODES] = N_EDGES;
}

__global__ __launch_bounds__(256) void scan_final_kernel(const int* __restrict__ counts,
                                                         const int* __restrict__ bexcl,
                                                         int* __restrict__ off,
                                                         int* __restrict__ cursor) {
    __shared__ int wsum[4];
    int tid = threadIdx.x;
    int lane = tid & 63, wid = tid >> 6;
    int i = blockIdx.x * 256 + tid;
    int v = (i < N_NODES) ? counts[i] : 0;
    int x = v;
#pragma unroll
    for (int d = 1; d < 64; d <<= 1) {
        int u = __shfl_up(x, d);
        if (lane >= d) x += u;
    }
    if (lane == 63) wsum[wid] = x;
    __syncthreads();
    int prefix = 0;
    for (int w = 0; w < wid; ++w) prefix += wsum[w];
    if (i < N_NODES) {
        int excl = bexcl[blockIdx.x] + prefix + x - v;
        off[i] = excl;
        cursor[i] = excl;
    }
}

// ---------------- CSR fill ----------------
__global__ __launch_bounds__(256) void fill_kernel(const int* __restrict__ src,
                                                   const int* __restrict__ dst,
                                                   int* __restrict__ cursor,
                                                   int* __restrict__ csr_src) {
    int e = blockIdx.x * blockDim.x + threadIdx.x;
    if (e < N_EDGES) {
        int pos = atomicAdd(&cursor[dst[e]], 1);
        csr_src[pos] = src[e];
    }
}

// ---------------- gather1: tb = z2 + P z3  (bf16 out) ----------------
// one wave/node; lane = slot*16 + colchunk; int4-aligned index group loads.
__global__ __launch_bounds__(256) void gather1_kernel(const unsigned short* __restrict__ z,
                                                      const int* __restrict__ off,
                                                      const int* __restrict__ csr_src,
                                                      unsigned short* __restrict__ tb) {
    unsigned n = (blockIdx.x * 256 + threadIdx.x) >> 6;
    if (n >= N_NODES) return;
    const int lane = threadIdx.x & 63;
    const int s = lane >> 4;
    const unsigned c = (lane & 15u) << 3;
    const unsigned short* fin = z + 256 + c;  // z3 cols
    const int2 ee = *(const int2*)(off + n);
    const int e0 = ee.x, e1 = ee.y;
    float acc[8] = {0.f, 0.f, 0.f, 0.f, 0.f, 0.f, 0.f, 0.f};
    for (int base = (e0 & ~3) + s * 4; base < e1; base += 16) {
        int4 idx = *(const int4*)(csr_src + base);
        float m0 = (base >= e0) ? 1.f : 0.f;
        float m1 = (base + 1 >= e0 && base + 1 < e1) ? 1.f : 0.f;
        float m2 = (base + 2 >= e0 && base + 2 < e1) ? 1.f : 0.f;
        float m3 = (base + 3 >= e0 && base + 3 < e1) ? 1.f : 0.f;
        int s0 = min(max(idx.x, 0), N_NODES - 1);
        int s1 = min(max(idx.y, 0), N_NODES - 1);
        int s2 = min(max(idx.z, 0), N_NODES - 1);
        int s3 = min(max(idx.w, 0), N_NODES - 1);
        ushort8 v0 = *(const ushort8*)(fin + (size_t)s0 * K3);
        ushort8 v1 = *(const ushort8*)(fin + (size_t)s1 * K3);
        ushort8 v2 = *(const ushort8*)(fin + (size_t)s2 * K3);
        ushort8 v3 = *(const ushort8*)(fin + (size_t)s3 * K3);
#pragma unroll
        for (int j = 0; j < 8; ++j)
            acc[j] += (m0 * bf2f(v0[j]) + m1 * bf2f(v1[j])) +
                      (m2 * bf2f(v2[j]) + m3 * bf2f(v3[j]));
    }
#pragma unroll
    for (int j = 0; j < 8; ++j) {
        acc[j] += __shfl_xor(acc[j], 16);
        acc[j] += __shfl_xor(acc[j], 32);
    }
    if (s == 0) {
        float inv = 1.0f / fmaxf((float)(e1 - e0), 1.0f);
        ushort8 za = *(const ushort8*)(z + (size_t)n * K3 + 128 + c);  // z2
        ushort8 o;
#pragma unroll
        for (int j = 0; j < 8; ++j) o[j] = f2bf(bf2f(za[j]) + acc[j] * inv);
        *(ushort8*)(tb + (size_t)n * D + c) = o;
    }
}

// ---------------- gather2: out = z1 + P tb  (fp32 out, final) ----------------
__global__ __launch_bounds__(256) void gather2_kernel(const unsigned short* __restrict__ z,
                                                      const unsigned short* __restrict__ tb,
                                                      const int* __restrict__ off,
                                                      const int* __restrict__ csr_src,
                                                      float* __restrict__ out) {
    unsigned n = (blockIdx.x * 256 + threadIdx.x) >> 6;
    if (n >= N_NODES) return;
    const int lane = threadIdx.x & 63;
    const int s = lane >> 4;
    const unsigned c = (lane & 15u) << 3;
    const unsigned short* fin = tb + c;
    const int2 ee = *(const int2*)(off + n);
    const int e0 = ee.x, e1 = ee.y;
    float acc[8] = {0.f, 0.f, 0.f, 0.f, 0.f, 0.f, 0.f, 0.f};
    for (int base = (e0 & ~3) + s * 4; base < e1; base += 16) {
        int4 idx = *(const int4*)(csr_src + base);
        float m0 = (base >= e0) ? 1.f : 0.f;
        float m1 = (base + 1 >= e0 && base + 1 < e1) ? 1.f : 0.f;
        float m2 = (base + 2 >= e0 && base + 2 < e1) ? 1.f : 0.f;
        float m3 = (base + 3 >= e0 && base + 3 < e1) ? 1.f : 0.f;
        int s0 = min(max(idx.x, 0), N_NODES - 1);
        int s1 = min(max(idx.y, 0), N_NODES - 1);
        int s2 = min(max(idx.z, 0), N_NODES - 1);
        int s3 = min(max(idx.w, 0), N_NODES - 1);
        ushort8 v0 = *(const ushort8*)(fin + (size_t)s0 * D);
        ushort8 v1 = *(const ushort8*)(fin + (size_t)s1 * D);
        ushort8 v2 = *(const ushort8*)(fin + (size_t)s2 * D);
        ushort8 v3 = *(const ushort8*)(fin + (size_t)s3 * D);
#pragma unroll
        for (int j = 0; j < 8; ++j)
            acc[j] += (m0 * bf2f(v0[j]) + m1 * bf2f(v1[j])) +
                      (m2 * bf2f(v2[j]) + m3 * bf2f(v3[j]));
    }
#pragma unroll
    for (int j = 0; j < 8; ++j) {
        acc[j] += __shfl_xor(acc[j], 16);
        acc[j] += __shfl_xor(acc[j], 32);
    }
    if (s == 0) {
        float inv = 1.0f / fmaxf((float)(e1 - e0), 1.0f);
        ushort8 za = *(const ushort8*)(z + (size_t)n * K3 + c);  // z1 (+bias)
        float4 q0, q1;
        q0.x = bf2f(za[0]) + acc[0] * inv;
        q0.y = bf2f(za[1]) + acc[1] * inv;
        q0.z = bf2f(za[2]) + acc[2] * inv;
        q0.w = bf2f(za[3]) + acc[3] * inv;
        q1.x = bf2f(za[4]) + acc[4] * inv;
        q1.y = bf2f(za[5]) + acc[5] * inv;
        q1.z = bf2f(za[6]) + acc[6] * inv;
        q1.w = bf2f(za[7]) + acc[7] * inv;
        *(float4*)(out + (size_t)n * D + c) = q0;
        *(float4*)(out + (size_t)n * D + c + 4) = q1;
    }
}

extern "C" void kernel_launch(void* const* d_in, const int* in_sizes, int n_in,
                              void* d_out, int out_size, void* d_ws, size_t ws_size,
                              hipStream_t stream) {
    const float* x = (const float*)d_in[0];
    const int* ei = (const int*)d_in[1];
    const float* W = (const float*)d_in[2];
    const float* b = (const float*)d_in[3];
    float* out = (float*)d_out;
    const int* src = ei;            // edge_index[0,:]
    const int* dst = ei + N_EDGES;  // edge_index[1,:]

    // workspace layout:
    //   xb [N,128] bf16 | z [N,384] bf16 | tb [N,128] bf16 | Wr 6144x16B
    //   counts [N] | bsum/bexcl [256+256] | off [N+1] | cursor [N] | csr_src [E+16]
    unsigned short* xb = (unsigned short*)d_ws;
    unsigned short* z = xb + (size_t)N_NODES * D;
    unsigned short* tb = z + (size_t)N_NODES * K3;
    unsigned short* Wr = tb + (size_t)N_NODES * D;
    int* counts = (int*)(Wr + 6144 * 8);
    int* bsum = counts + N_NODES;
    int* bexcl = bsum + 256;
    int* off = bexcl + 256;
    int* cursor = off + (N_NODES + 1);
    int* csr_src = cursor + N_NODES;

    const int NB = (N_NODES + 255) / 256;  // 196

    prep_kernel<<<800, 256, 0, stream>>>(x, W, xb, Wr, counts);
    gemmhist_kernel<<<NB_G + NB_H, 256, 0, stream>>>(xb, Wr, b, dst, z, counts);
    bsum_kernel<<<NB, 256, 0, stream>>>(counts, bsum);
    scan_bsum_kernel<<<1, 256, 0, stream>>>(bsum, bexcl, off, NB);
    scan_final_kernel<<<NB, 256, 0, stream>>>(counts, bexcl, off, cursor);
    fill_kernel<<<(N_EDGES + 255) / 256, 256, 0, stream>>>(src, dst, cursor, csr_src);

    const int ggrid = (N_NODES * 64 + 255) / 256;  // one wave per node
    gather1_kernel<<<ggrid, 256, 0, stream>>>(z, off, csr_src, tb);
    gather2_kernel<<<ggrid, 256, 0, stream>>>(z, tb, off, csr_src, out);
}